// Round 7
// baseline (796.450 us; speedup 1.0000x reference)
//
#include <hip/hip_runtime.h>

#define BIGF 1e20f
#define VF   1e10f

constexpr float SQ2 = 1.41421356237309515f;  // fp32 0x3FB504F3, == jnp.sqrt(2.0) in f32

// ---------------------------------------------------------------------------
// DPP wave shifts (direction-symmetric usage only: the 3pt step is l/r sym).
// ---------------------------------------------------------------------------
__device__ __forceinline__ float dpp_left(float x)
{
    int o = __builtin_amdgcn_update_dpp(0x60AD78ECu /*1e20f*/, __float_as_int(x),
                                        0x138, 0xF, 0xF, false);
    return __int_as_float(o);
}
__device__ __forceinline__ float dpp_right(float x)
{
    int o = __builtin_amdgcn_update_dpp(0x60AD78ECu /*1e20f*/, __float_as_int(x),
                                        0x130, 0xF, 0xF, false);
    return __int_as_float(o);
}

// ---------------------------------------------------------------------------
// K1: binarize + channel max + dist init.  maps 0..15 = pred, 16..31 = target
// ---------------------------------------------------------------------------
__global__ __launch_bounds__(256) void k_init(const float* __restrict__ pred,
                                              const float* __restrict__ tgt,
                                              float* __restrict__ bufA,
                                              float* __restrict__ acc,
                                              unsigned* __restrict__ count)
{
    if (blockIdx.x == 0 && threadIdx.x == 0) { *acc = 0.0f; *count = 0u; }
    int r = blockIdx.x & 7;
    int k = blockIdx.x >> 3;
    int b = r + 8 * (k >> 10);
    int pix = (k & 1023) * 256 + threadIdx.x;
    long base = (long)b * 3 * 262144 + pix;

    float p0 = pred[base], p1 = pred[base + 262144], p2 = pred[base + 2 * 262144];
    bool fgP = ((p0 + 1.0f) * 0.5f >= 0.7f) ||
               ((p1 + 1.0f) * 0.5f >= 0.7f) ||
               ((p2 + 1.0f) * 0.5f >= 0.7f);

    float t0 = tgt[base], t1 = tgt[base + 262144], t2 = tgt[base + 2 * 262144];
    float mt = fmaxf(fmaxf(t0, t1), t2);

    bufA[(long)b * 262144 + pix]        = fgP ? 0.0f : VF;
    bufA[(long)(16 + b) * 262144 + pix] = VF * (1.0f - mt);
}

// ---------------------------------------------------------------------------
// K2: scan-decomposed chamfer sweep. 1 WG (1024 thr = 16 waves) per map.
// down: X->Y (row-major); up: Y->X written TRANSPOSED (fuses the transpose).
// Each of the 4 identical k_sweep calls = updown(dim0) + net transpose.
// ---------------------------------------------------------------------------
__device__ __forceinline__ void load_row8(const float* __restrict__ M, int r, int c0, float v[8])
{
    const float4* q = (const float4*)(M + ((long)r << 9) + c0);
    float4 a = q[0], b = q[1];
    v[0] = a.x; v[1] = a.y; v[2] = a.z; v[3] = a.w;
    v[4] = b.x; v[5] = b.y; v[6] = b.z; v[7] = b.w;
}
__device__ __forceinline__ void store_row8(float* __restrict__ M, int r, int c0, const float v[8])
{
    float4* q = (float4*)(M + ((long)r << 9) + c0);
    q[0] = make_float4(v[0], v[1], v[2], v[3]);
    q[1] = make_float4(v[4], v[5], v[6], v[7]);
}
__device__ __forceinline__ void load8_lds(const float* p, float v[8])
{
    float4 a = *(const float4*)p; float4 b = *(const float4*)(p + 4);
    v[0] = a.x; v[1] = a.y; v[2] = a.z; v[3] = a.w;
    v[4] = b.x; v[5] = b.y; v[6] = b.z; v[7] = b.w;
}

// 3pt chamfer step: p <- min(cur, p+1, min(neighbors)+SQ2)
__device__ __forceinline__ void step8(const float cur[8], float p[8], float nv[8])
{
    float left  = dpp_left(p[7]);
    float right = dpp_right(p[0]);
    #pragma unroll
    for (int j = 0; j < 8; ++j) {
        float l  = (j == 0) ? left  : p[j - 1];
        float rr = (j == 7) ? right : p[j + 1];
        nv[j] = fminf(fminf(cur[j], p[j] + 1.0f), fminf(l, rr) + SQ2);
    }
}

// Chain over rows i=I0..31 of a 32-row block starting at row `a`.
// DIR=+1: rows a+i ascending.  DIR=-1: rows a+31-i descending.
// MODE: 0 = no store (phase 1), 1 = row-major store, 2 = transposed store.
template<int DIR, int MODE, bool TRACK, int I0>
__device__ __forceinline__ void chain32(const float* __restrict__ S, float* __restrict__ D,
                                        int c0, int a, float p[8], float& mn, float& mx,
                                        float (*colbuf)[4])
{
    float buf[3][8];
    load_row8(S, (DIR > 0) ? a + I0 : a + 31 - I0, c0, buf[I0 % 3]);
    load_row8(S, (DIR > 0) ? a + I0 + 1 : a + 31 - (I0 + 1), c0, buf[(I0 + 1) % 3]);
    #pragma unroll
    for (int i = I0; i < 32; ++i) {
        const int r  = (DIR > 0) ? a + i : a + 31 - i;
        const int r4 = (DIR > 0) ? (i & 3) : ((31 - i) & 3);   // == r & 3 (a % 32 == 0)
        if (i + 2 < 32)
            load_row8(S, (DIR > 0) ? a + i + 2 : a + 31 - (i + 2), c0, buf[(i + 2) % 3]);
        float nv[8];
        step8(buf[i % 3], p, nv);
        if constexpr (MODE == 1) store_row8(D, r, c0, nv);
        #pragma unroll
        for (int j = 0; j < 8; ++j) {
            p[j] = nv[j];
            if constexpr (TRACK) { mn = fminf(mn, nv[j]); mx = fmaxf(mx, nv[j]); }
            if constexpr (MODE == 2) colbuf[j][r4] = nv[j];
        }
        if constexpr (MODE == 2) {
            if (r4 == 0) {
                #pragma unroll
                for (int j = 0; j < 8; ++j)
                    *(float4*)(D + (long)(c0 + j) * 512 + r) =
                        make_float4(colbuf[j][0], colbuf[j][1], colbuf[j][2], colbuf[j][3]);
            }
        }
    }
}

// One boundary combine: bwp[wdst] = min(bwp[wdst], cone32(bwp[wsrc])).
// Waves 0..8 split the 65 Delta values; LDS partial reduce.
__device__ __forceinline__ void combine(float* __restrict__ bwp, float* __restrict__ part,
                                        int wdst, int wsrc, int t, int wave, int lane,
                                        const float wreg[8])
{
    const float* bs = bwp + wsrc * 576;
    if (wave <= 8) {
        int base = lane * 8 + 8 * wave;
        float W[16];
        float4 W0 = *(const float4*)(bs + base);
        float4 W1 = *(const float4*)(bs + base + 4);
        W[0]=W0.x; W[1]=W0.y; W[2]=W0.z; W[3]=W0.w;
        W[4]=W1.x; W[5]=W1.y; W[6]=W1.z; W[7]=W1.w;
        float acc[8];
        if (wave < 8) {
            float4 W2 = *(const float4*)(bs + base + 8);
            float4 W3 = *(const float4*)(bs + base + 12);
            W[8]=W2.x; W[9]=W2.y; W[10]=W2.z; W[11]=W2.w;
            W[12]=W3.x; W[13]=W3.y; W[14]=W3.z; W[15]=W3.w;
            #pragma unroll
            for (int j = 0; j < 8; ++j) acc[j] = W[j] + wreg[0];
            #pragma unroll
            for (int dt = 1; dt < 8; ++dt)
                #pragma unroll
                for (int j = 0; j < 8; ++j)
                    acc[j] = fminf(acc[j], W[j + dt] + wreg[dt]);
        } else {               // Delta = +32 only
            #pragma unroll
            for (int j = 0; j < 8; ++j) acc[j] = W[j] + wreg[0];
        }
        float4* pp = (float4*)(part + wave * 512 + lane * 8);
        pp[0] = make_float4(acc[0], acc[1], acc[2], acc[3]);
        pp[1] = make_float4(acc[4], acc[5], acc[6], acc[7]);
    }
    __syncthreads();
    if (t < 512) {
        float r = bwp[wdst * 576 + 32 + t];
        #pragma unroll
        for (int p2 = 0; p2 < 9; ++p2) r = fminf(r, part[p2 * 512 + t]);
        bwp[wdst * 576 + 32 + t] = r;
    }
    __syncthreads();
}

__global__ __launch_bounds__(1024) void k_sweep(float* __restrict__ X0,
                                                float* __restrict__ Y0,
                                                float* __restrict__ minmax,
                                                int final_pass)
{
    __shared__ __align__(16) float bwp[16 * 576];   // padded boundary rows
    __shared__ __align__(16) float part[9 * 512];
    __shared__ float wgt[72];
    __shared__ float red[32];

    const int m = blockIdx.x;
    float* X = X0 + ((long)m << 18);
    float* Y = Y0 + ((long)m << 18);
    const int t = threadIdx.x;
    const int wave = t >> 6, lane = t & 63;
    const int c0 = lane << 3;
    const int a  = wave << 5;

    // pads (BIG) for all 16 bwp rows + weight table w(|D|) = |D|*sqrt2 + (32-|D|)
    bwp[wave * 576 + ((lane < 32) ? lane : lane + 512)] = BIGF;
    if (t < 65) { int d = t - 32; int ad = d < 0 ? -d : d; wgt[t] = ad * SQ2 + (float)(32 - ad); }
    __syncthreads();
    float wreg[8];
    #pragma unroll
    for (int dt = 0; dt < 8; ++dt) wreg[dt] = BIGF;
    if (wave < 8) {
        #pragma unroll
        for (int dt = 0; dt < 8; ++dt) wreg[dt] = wgt[wave * 8 + dt];
    } else if (wave == 8) wreg[0] = wgt[64];

    float mn = BIGF, mx = -BIGF;
    float dmy0, dmy1;

    // ================= DOWN (X -> Y, row-major) =================
    {   // phase 1: internal DT, keep last row
        float p[8];
        load_row8(X, a, c0, p);
        chain32<1, 0, false, 1>(X, Y, c0, a, p, dmy0, dmy1, nullptr);
        *(float4*)(bwp + wave * 576 + 32 + c0)     = make_float4(p[0], p[1], p[2], p[3]);
        *(float4*)(bwp + wave * 576 + 32 + c0 + 4) = make_float4(p[4], p[5], p[6], p[7]);
    }
    __syncthreads();
    #pragma unroll 1
    for (int w2 = 1; w2 < 16; ++w2) combine(bwp, part, w2, w2 - 1, t, wave, lane, wreg);
    {   // phase 3: exact recurrence from boundary seeds
        float p[8];
        if (wave == 0) {
            load_row8(X, 0, c0, p);
            store_row8(Y, 0, c0, p);
            chain32<1, 1, false, 1>(X, Y, c0, a, p, dmy0, dmy1, nullptr);
        } else {
            load8_lds(bwp + (wave - 1) * 576 + 32 + c0, p);
            chain32<1, 1, false, 0>(X, Y, c0, a, p, dmy0, dmy1, nullptr);
        }
    }
    __syncthreads();

    // ================= UP (Y -> X, transposed write) =================
    {   // phase 1
        float p[8];
        load_row8(Y, a + 31, c0, p);
        chain32<-1, 0, false, 1>(Y, X, c0, a, p, dmy0, dmy1, nullptr);
        *(float4*)(bwp + wave * 576 + 32 + c0)     = make_float4(p[0], p[1], p[2], p[3]);
        *(float4*)(bwp + wave * 576 + 32 + c0 + 4) = make_float4(p[4], p[5], p[6], p[7]);
    }
    __syncthreads();
    #pragma unroll 1
    for (int w2 = 14; w2 >= 0; --w2) combine(bwp, part, w2, w2 + 1, t, wave, lane, wreg);
    {   // phase 3 (always tracks min/max; written only on final_pass)
        float colbuf[8][4];
        float p[8];
        if (wave == 15) {
            load_row8(Y, 511, c0, p);
            #pragma unroll
            for (int j = 0; j < 8; ++j) {
                colbuf[j][3] = p[j];
                mn = fminf(mn, p[j]); mx = fmaxf(mx, p[j]);
            }
            chain32<-1, 2, true, 1>(Y, X, c0, a, p, mn, mx, colbuf);
        } else {
            load8_lds(bwp + (wave + 1) * 576 + 32 + c0, p);
            chain32<-1, 2, true, 0>(Y, X, c0, a, p, mn, mx, colbuf);
        }
    }

    if (final_pass) {
        for (int o = 32; o > 0; o >>= 1) {
            mn = fminf(mn, __shfl_down(mn, o));
            mx = fmaxf(mx, __shfl_down(mx, o));
        }
        if (lane == 0) { red[2 * wave] = mn; red[2 * wave + 1] = mx; }
        __syncthreads();
        if (t == 0) {
            #pragma unroll
            for (int i = 1; i < 16; ++i) {
                mn = fminf(mn, red[2 * i]); mx = fmaxf(mx, red[2 * i + 1]);
            }
            minmax[2 * m] = mn; minmax[2 * m + 1] = mx;
        }
    }
}

// ---------------------------------------------------------------------------
// K4: register-blocked bitonic sort (8 elems/thread) + MSE + fused finalize.
// ---------------------------------------------------------------------------
__device__ __forceinline__ void ce(float& a, float& b, bool up)
{
    float lo = fminf(a, b), hi = fmaxf(a, b);
    a = up ? lo : hi;
    b = up ? hi : lo;
}
__device__ __forceinline__ void merge8(float v[8], bool up)
{
    ce(v[0], v[4], up); ce(v[1], v[5], up); ce(v[2], v[6], up); ce(v[3], v[7], up);
    ce(v[0], v[2], up); ce(v[1], v[3], up); ce(v[4], v[6], up); ce(v[5], v[7], up);
    ce(v[0], v[1], up); ce(v[2], v[3], up); ce(v[4], v[5], up); ce(v[6], v[7], up);
}
__device__ __forceinline__ void sort8(float v[8], bool u8)
{
    ce(v[0], v[1], true);  ce(v[2], v[3], false);
    ce(v[4], v[5], true);  ce(v[6], v[7], false);
    ce(v[0], v[2], true);  ce(v[1], v[3], true);
    ce(v[4], v[6], false); ce(v[5], v[7], false);
    ce(v[0], v[1], true);  ce(v[2], v[3], true);
    ce(v[4], v[5], false); ce(v[6], v[7], false);
    merge8(v, u8);
}
__device__ __forceinline__ void xstage(float v[8], int j8, bool keepmin)
{
    #pragma unroll
    for (int e = 0; e < 8; ++e) {
        float o = __shfl_xor(v[e], j8);
        v[e] = keepmin ? fminf(v[e], o) : fmaxf(v[e], o);
    }
}
__device__ __forceinline__ void lstage2(float p[8], float q[8], int j8, bool keepmin,
                                        float* sp, float* st, int t)
{
    __syncthreads();
    float4* wp = (float4*)(sp + t * 8);
    float4* wq = (float4*)(st + t * 8);
    wp[0] = make_float4(p[0], p[1], p[2], p[3]);
    wp[1] = make_float4(p[4], p[5], p[6], p[7]);
    wq[0] = make_float4(q[0], q[1], q[2], q[3]);
    wq[1] = make_float4(q[4], q[5], q[6], q[7]);
    __syncthreads();
    int pt = t ^ j8;
    const float4* rp = (const float4*)(sp + pt * 8);
    const float4* rq = (const float4*)(st + pt * 8);
    float4 a = rp[0], bb = rp[1], c = rq[0], d = rq[1];
    float op[8] = {a.x, a.y, a.z, a.w, bb.x, bb.y, bb.z, bb.w};
    float oq[8] = {c.x, c.y, c.z, c.w, d.x, d.y, d.z, d.w};
    #pragma unroll
    for (int e = 0; e < 8; ++e) {
        p[e] = keepmin ? fminf(p[e], op[e]) : fmaxf(p[e], op[e]);
        q[e] = keepmin ? fminf(q[e], oq[e]) : fmaxf(q[e], oq[e]);
    }
}

__global__ __launch_bounds__(512) void k_loss(const float* __restrict__ bufB,
                                              const float* __restrict__ minmax,
                                              float* __restrict__ acc,
                                              unsigned* __restrict__ count,
                                              float* __restrict__ out)
{
    __shared__ float sp[4096];
    __shared__ float st[4096];
    __shared__ float rs[8];

    int t = threadIdx.x;
    int r = blockIdx.x & 7;
    int k = blockIdx.x >> 3;
    int b = r + 8 * (k >> 6);
    int w = k & 63;
    int wi = w >> 3, wj = w & 7;

    int i0 = t << 3;
    int y = wi * 64 + (i0 >> 6);
    int x = wj * 64 + (i0 & 63);

    float mnP = minmax[2 * b],        mxP = minmax[2 * b + 1];
    float mnT = minmax[2 * (16 + b)], mxT = minmax[2 * (16 + b) + 1];
    float sclP = 1.0f / (mxP - mnP + 1e-6f);
    float sclT = 1.0f / (mxT - mnT + 1e-6f);

    float p[8], q[8];
    {
        const float4* P4 = (const float4*)(bufB + (long)b * 262144 + y * 512 + x);
        const float4* T4 = (const float4*)(bufB + (long)(16 + b) * 262144 + y * 512 + x);
        float4 a = P4[0], bb = P4[1], c = T4[0], d = T4[1];
        p[0]=a.x; p[1]=a.y; p[2]=a.z; p[3]=a.w; p[4]=bb.x; p[5]=bb.y; p[6]=bb.z; p[7]=bb.w;
        q[0]=c.x; q[1]=c.y; q[2]=c.z; q[3]=c.w; q[4]=d.x;  q[5]=d.y;  q[6]=d.z;  q[7]=d.w;
        #pragma unroll
        for (int e = 0; e < 8; ++e) {
            p[e] = (p[e] - mnP) * sclP;
            q[e] = (q[e] - mnT) * sclT;
        }
    }

    bool u8 = ((t & 1) == 0);
    sort8(p, u8);
    sort8(q, u8);

    for (int kk = 16; kk <= 4096; kk <<= 1) {
        bool u = ((i0 & kk) == 0);
        for (int j = kk >> 1; j >= 8; j >>= 1) {
            bool l = ((i0 & j) == 0);
            bool keepmin = (u == l);
            int j8 = j >> 3;
            if (j8 < 64) {
                xstage(p, j8, keepmin);
                xstage(q, j8, keepmin);
            } else {
                lstage2(p, q, j8, keepmin, sp, st, t);
            }
        }
        merge8(p, u);
        merge8(q, u);
    }

    float s = 0.0f;
    #pragma unroll
    for (int e = 0; e < 8; ++e) { float d = p[e] - q[e]; s += d * d; }
    for (int o = 32; o > 0; o >>= 1) s += __shfl_down(s, o);
    if ((t & 63) == 0) rs[t >> 6] = s;
    __syncthreads();
    if (t == 0) {
        float tot = 0.0f;
        #pragma unroll
        for (int i = 0; i < 8; ++i) tot += rs[i];
        atomicAdd(acc, tot);
        __threadfence();
        unsigned done = atomicAdd(count, 1u);
        if (done == 1023u) {
            float total = atomicAdd(acc, 0.0f);
            float mean = total * (1.0f / 4194304.0f);
            out[0] = mean * 0.005f;
            out[1] = mean;
        }
    }
}

extern "C" void kernel_launch(void* const* d_in, const int* in_sizes, int n_in,
                              void* d_out, int out_size, void* d_ws, size_t ws_size,
                              hipStream_t stream)
{
    const float* pred = (const float*)d_in[0];
    const float* tgt  = (const float*)d_in[1];
    float* out = (float*)d_out;

    char* ws = (char*)d_ws;
    float* bufA     = (float*)ws;                     // 32 MB
    float* bufB     = (float*)(ws + (32ull << 20));   // 32 MB scratch
    float* minmax   = (float*)(ws + (64ull << 20));   // 64 floats
    float* acc      = minmax + 64;
    unsigned* count = (unsigned*)(acc + 1);

    k_init <<<16 * 1024, 256, 0, stream>>>(pred, tgt, bufA, acc, count);
    // each k_sweep: updown over dim0 of A + net transpose (result back in A)
    k_sweep<<<32, 1024, 0, stream>>>(bufA, bufB, minmax, 0);  // rows,  iter 1
    k_sweep<<<32, 1024, 0, stream>>>(bufA, bufB, minmax, 0);  // cols,  iter 1
    k_sweep<<<32, 1024, 0, stream>>>(bufA, bufB, minmax, 0);  // rows,  iter 2
    k_sweep<<<32, 1024, 0, stream>>>(bufA, bufB, minmax, 1);  // cols,  iter 2 (+minmax)
    k_loss <<<1024, 512, 0, stream>>>(bufA, minmax, acc, count, out);
}

// Round 8
// 695.974 us; speedup vs baseline: 1.1444x; 1.1444x over previous
//
#include <hip/hip_runtime.h>

#define BIGF 1e20f
#define VF   1e10f

constexpr float SQ2 = 1.41421356237309515f;  // fp32 0x3FB504F3, == jnp.sqrt(2.0) in f32

// ---------------------------------------------------------------------------
// DPP wave shifts (direction-symmetric usage only: the 3pt step is l/r sym).
// ---------------------------------------------------------------------------
__device__ __forceinline__ float dpp_left(float x)
{
    int o = __builtin_amdgcn_update_dpp(0x60AD78ECu /*1e20f*/, __float_as_int(x),
                                        0x138, 0xF, 0xF, false);
    return __int_as_float(o);
}
__device__ __forceinline__ float dpp_right(float x)
{
    int o = __builtin_amdgcn_update_dpp(0x60AD78ECu /*1e20f*/, __float_as_int(x),
                                        0x130, 0xF, 0xF, false);
    return __int_as_float(o);
}

// ---------------------------------------------------------------------------
// K1: binarize + channel max + dist init.  maps 0..15 = pred, 16..31 = target
// ---------------------------------------------------------------------------
__global__ __launch_bounds__(256) void k_init(const float* __restrict__ pred,
                                              const float* __restrict__ tgt,
                                              float* __restrict__ bufA,
                                              float* __restrict__ acc,
                                              unsigned* __restrict__ count)
{
    if (blockIdx.x == 0 && threadIdx.x == 0) { *acc = 0.0f; *count = 0u; }
    int r = blockIdx.x & 7;
    int k = blockIdx.x >> 3;
    int b = r + 8 * (k >> 10);
    int pix = (k & 1023) * 256 + threadIdx.x;
    long base = (long)b * 3 * 262144 + pix;

    float p0 = pred[base], p1 = pred[base + 262144], p2 = pred[base + 2 * 262144];
    bool fgP = ((p0 + 1.0f) * 0.5f >= 0.7f) ||
               ((p1 + 1.0f) * 0.5f >= 0.7f) ||
               ((p2 + 1.0f) * 0.5f >= 0.7f);

    float t0 = tgt[base], t1 = tgt[base + 262144], t2 = tgt[base + 2 * 262144];
    float mt = fmaxf(fmaxf(t0, t1), t2);

    bufA[(long)b * 262144 + pix]        = fgP ? 0.0f : VF;
    bufA[(long)(16 + b) * 262144 + pix] = VF * (1.0f - mt);
}

// ---------------------------------------------------------------------------
// K2: scan-decomposed chamfer sweep. 1 WG (1024 thr = 16 waves) per map.
// down: X->Y; up: Y->X. Both stores row-major coalesced. Result in X.
// ---------------------------------------------------------------------------
__device__ __forceinline__ void load_row8(const float* __restrict__ M, int r, int c0, float v[8])
{
    const float4* q = (const float4*)(M + ((long)r << 9) + c0);
    float4 a = q[0], b = q[1];
    v[0] = a.x; v[1] = a.y; v[2] = a.z; v[3] = a.w;
    v[4] = b.x; v[5] = b.y; v[6] = b.z; v[7] = b.w;
}
__device__ __forceinline__ void store_row8(float* __restrict__ M, int r, int c0, const float v[8])
{
    float4* q = (float4*)(M + ((long)r << 9) + c0);
    q[0] = make_float4(v[0], v[1], v[2], v[3]);
    q[1] = make_float4(v[4], v[5], v[6], v[7]);
}
__device__ __forceinline__ void load8_lds(const float* p, float v[8])
{
    float4 a = *(const float4*)p; float4 b = *(const float4*)(p + 4);
    v[0] = a.x; v[1] = a.y; v[2] = a.z; v[3] = a.w;
    v[4] = b.x; v[5] = b.y; v[6] = b.z; v[7] = b.w;
}

// 3pt chamfer step: nv <- min(cur, p+1, min(neighbors)+SQ2)
__device__ __forceinline__ void step8(const float cur[8], float p[8], float nv[8])
{
    float left  = dpp_left(p[7]);
    float right = dpp_right(p[0]);
    #pragma unroll
    for (int j = 0; j < 8; ++j) {
        float l  = (j == 0) ? left  : p[j - 1];
        float rr = (j == 7) ? right : p[j + 1];
        nv[j] = fminf(fminf(cur[j], p[j] + 1.0f), fminf(l, rr) + SQ2);
    }
}

// Chain over rows i=I0..31 of a 32-row block at row `a`. Depth-3 prefetch.
// DIR=+1: rows a+i ascending. DIR=-1: rows a+31-i descending.
// MODE: 0 = no store (phase 1), 1 = row-major store (phase 3).
template<int DIR, int MODE, bool TRACK, int I0>
__device__ __forceinline__ void chain32(const float* __restrict__ S, float* __restrict__ D,
                                        int c0, int a, float p[8], float& mn, float& mx)
{
    float buf[4][8];
    #pragma unroll
    for (int k = 0; k < 3; ++k) {
        int i = I0 + k;
        if (i < 32) load_row8(S, (DIR > 0) ? a + i : a + 31 - i, c0, buf[i & 3]);
    }
    #pragma unroll
    for (int i = I0; i < 32; ++i) {
        if (i + 3 < 32)
            load_row8(S, (DIR > 0) ? a + i + 3 : a + 31 - (i + 3), c0, buf[(i + 3) & 3]);
        float nv[8];
        step8(buf[i & 3], p, nv);
        if constexpr (MODE == 1) store_row8(D, (DIR > 0) ? a + i : a + 31 - i, c0, nv);
        #pragma unroll
        for (int j = 0; j < 8; ++j) {
            p[j] = nv[j];
            if constexpr (TRACK) { mn = fminf(mn, nv[j]); mx = fmaxf(mx, nv[j]); }
        }
    }
}

// One boundary combine: bwp[wdst] = min(bwp[wdst], cone32(bwp[wsrc])).
// Waves 0..8 split the 65 Delta values; LDS partial reduce.
__device__ __forceinline__ void combine(float* __restrict__ bwp, float* __restrict__ part,
                                        int wdst, int wsrc, int t, int wave, int lane,
                                        const float wreg[8])
{
    const float* bs = bwp + wsrc * 576;
    if (wave <= 8) {
        int base = lane * 8 + 8 * wave;
        float W[16];
        float4 W0 = *(const float4*)(bs + base);
        float4 W1 = *(const float4*)(bs + base + 4);
        W[0]=W0.x; W[1]=W0.y; W[2]=W0.z; W[3]=W0.w;
        W[4]=W1.x; W[5]=W1.y; W[6]=W1.z; W[7]=W1.w;
        float acc[8];
        if (wave < 8) {
            float4 W2 = *(const float4*)(bs + base + 8);
            float4 W3 = *(const float4*)(bs + base + 12);
            W[8]=W2.x; W[9]=W2.y; W[10]=W2.z; W[11]=W2.w;
            W[12]=W3.x; W[13]=W3.y; W[14]=W3.z; W[15]=W3.w;
            #pragma unroll
            for (int j = 0; j < 8; ++j) acc[j] = W[j] + wreg[0];
            #pragma unroll
            for (int dt = 1; dt < 8; ++dt)
                #pragma unroll
                for (int j = 0; j < 8; ++j)
                    acc[j] = fminf(acc[j], W[j + dt] + wreg[dt]);
        } else {               // Delta = +32 only
            #pragma unroll
            for (int j = 0; j < 8; ++j) acc[j] = W[j] + wreg[0];
        }
        float4* pp = (float4*)(part + wave * 512 + lane * 8);
        pp[0] = make_float4(acc[0], acc[1], acc[2], acc[3]);
        pp[1] = make_float4(acc[4], acc[5], acc[6], acc[7]);
    }
    __syncthreads();
    if (t < 512) {
        float r = bwp[wdst * 576 + 32 + t];
        #pragma unroll
        for (int p2 = 0; p2 < 9; ++p2) r = fminf(r, part[p2 * 512 + t]);
        bwp[wdst * 576 + 32 + t] = r;
    }
    __syncthreads();
}

__global__ __launch_bounds__(1024, 1) void k_sweep(float* __restrict__ X0,
                                                   float* __restrict__ Y0,
                                                   float* __restrict__ minmax,
                                                   int final_pass)
{
    __shared__ __align__(16) float bwp[16 * 576];   // padded boundary rows
    __shared__ __align__(16) float part[9 * 512];
    __shared__ float wgt[72];
    __shared__ float red[32];

    const int m = blockIdx.x;
    float* X = X0 + ((long)m << 18);
    float* Y = Y0 + ((long)m << 18);
    const int t = threadIdx.x;
    const int wave = t >> 6, lane = t & 63;
    const int c0 = lane << 3;
    const int a  = wave << 5;

    bwp[wave * 576 + ((lane < 32) ? lane : lane + 512)] = BIGF;
    if (t < 65) { int d = t - 32; int ad = d < 0 ? -d : d; wgt[t] = ad * SQ2 + (float)(32 - ad); }
    __syncthreads();
    float wreg[8];
    #pragma unroll
    for (int dt = 0; dt < 8; ++dt) wreg[dt] = BIGF;
    if (wave < 8) {
        #pragma unroll
        for (int dt = 0; dt < 8; ++dt) wreg[dt] = wgt[wave * 8 + dt];
    } else if (wave == 8) wreg[0] = wgt[64];

    float mn = BIGF, mx = -BIGF;
    float dmy0, dmy1;

    // ================= DOWN (X -> Y) =================
    {   // phase 1: internal DT, keep last row
        float p[8];
        load_row8(X, a, c0, p);
        chain32<1, 0, false, 1>(X, Y, c0, a, p, dmy0, dmy1);
        *(float4*)(bwp + wave * 576 + 32 + c0)     = make_float4(p[0], p[1], p[2], p[3]);
        *(float4*)(bwp + wave * 576 + 32 + c0 + 4) = make_float4(p[4], p[5], p[6], p[7]);
    }
    __syncthreads();
    #pragma unroll 1
    for (int w2 = 1; w2 < 16; ++w2) combine(bwp, part, w2, w2 - 1, t, wave, lane, wreg);
    {   // phase 3: exact recurrence from boundary seeds
        float p[8];
        if (wave == 0) {
            load_row8(X, 0, c0, p);
            store_row8(Y, 0, c0, p);
            chain32<1, 1, false, 1>(X, Y, c0, a, p, dmy0, dmy1);
        } else {
            load8_lds(bwp + (wave - 1) * 576 + 32 + c0, p);
            chain32<1, 1, false, 0>(X, Y, c0, a, p, dmy0, dmy1);
        }
    }
    __syncthreads();

    // ================= UP (Y -> X) =================
    {   // phase 1
        float p[8];
        load_row8(Y, a + 31, c0, p);
        chain32<-1, 0, false, 1>(Y, X, c0, a, p, dmy0, dmy1);
        *(float4*)(bwp + wave * 576 + 32 + c0)     = make_float4(p[0], p[1], p[2], p[3]);
        *(float4*)(bwp + wave * 576 + 32 + c0 + 4) = make_float4(p[4], p[5], p[6], p[7]);
    }
    __syncthreads();
    #pragma unroll 1
    for (int w2 = 14; w2 >= 0; --w2) combine(bwp, part, w2, w2 + 1, t, wave, lane, wreg);
    {   // phase 3 (tracks min/max; row-major coalesced store)
        float p[8];
        if (wave == 15) {
            load_row8(Y, 511, c0, p);
            store_row8(X, 511, c0, p);
            #pragma unroll
            for (int j = 0; j < 8; ++j) { mn = fminf(mn, p[j]); mx = fmaxf(mx, p[j]); }
            chain32<-1, 1, true, 1>(Y, X, c0, a, p, mn, mx);
        } else {
            load8_lds(bwp + (wave + 1) * 576 + 32 + c0, p);
            chain32<-1, 1, true, 0>(Y, X, c0, a, p, mn, mx);
        }
    }

    if (final_pass) {
        for (int o = 32; o > 0; o >>= 1) {
            mn = fminf(mn, __shfl_down(mn, o));
            mx = fmaxf(mx, __shfl_down(mx, o));
        }
        if (lane == 0) { red[2 * wave] = mn; red[2 * wave + 1] = mx; }
        __syncthreads();
        if (t == 0) {
            #pragma unroll
            for (int i = 1; i < 16; ++i) {
                mn = fminf(mn, red[2 * i]); mx = fmaxf(mx, red[2 * i + 1]);
            }
            minmax[2 * m] = mn; minmax[2 * m + 1] = mx;
        }
    }
}

// ---------------------------------------------------------------------------
// K3: transpose, 64x64 tiles, fully parallel (32 maps x 64 tiles blocks)
// ---------------------------------------------------------------------------
__global__ __launch_bounds__(256) void k_transpose(const float* __restrict__ src,
                                                   float* __restrict__ dst)
{
    __shared__ float tile[64][65];
    int r = blockIdx.x & 7;
    int k = blockIdx.x >> 3;
    int m = r + 8 * (k >> 6);
    int tidx = k & 63;
    int ti = tidx >> 3, tj = tidx & 7;
    const float* S = src + ((long)m << 18);
    float*       D = dst + ((long)m << 18);
    int x = threadIdx.x & 63, y0 = threadIdx.x >> 6;
    #pragma unroll
    for (int kk = 0; kk < 16; ++kk) {
        int y = y0 + (kk << 2);
        tile[y][x] = S[(ti * 64 + y) * 512 + tj * 64 + x];
    }
    __syncthreads();
    #pragma unroll
    for (int kk = 0; kk < 16; ++kk) {
        int y = y0 + (kk << 2);
        D[(tj * 64 + y) * 512 + ti * 64 + x] = tile[x][y];
    }
}

// ---------------------------------------------------------------------------
// K4: register-blocked bitonic sort (8 elems/thread) + MSE + fused finalize.
// ---------------------------------------------------------------------------
__device__ __forceinline__ void ce(float& a, float& b, bool up)
{
    float lo = fminf(a, b), hi = fmaxf(a, b);
    a = up ? lo : hi;
    b = up ? hi : lo;
}
__device__ __forceinline__ void merge8(float v[8], bool up)
{
    ce(v[0], v[4], up); ce(v[1], v[5], up); ce(v[2], v[6], up); ce(v[3], v[7], up);
    ce(v[0], v[2], up); ce(v[1], v[3], up); ce(v[4], v[6], up); ce(v[5], v[7], up);
    ce(v[0], v[1], up); ce(v[2], v[3], up); ce(v[4], v[5], up); ce(v[6], v[7], up);
}
__device__ __forceinline__ void sort8(float v[8], bool u8)
{
    ce(v[0], v[1], true);  ce(v[2], v[3], false);
    ce(v[4], v[5], true);  ce(v[6], v[7], false);
    ce(v[0], v[2], true);  ce(v[1], v[3], true);
    ce(v[4], v[6], false); ce(v[5], v[7], false);
    ce(v[0], v[1], true);  ce(v[2], v[3], true);
    ce(v[4], v[5], false); ce(v[6], v[7], false);
    merge8(v, u8);
}
__device__ __forceinline__ void xstage(float v[8], int j8, bool keepmin)
{
    #pragma unroll
    for (int e = 0; e < 8; ++e) {
        float o = __shfl_xor(v[e], j8);
        v[e] = keepmin ? fminf(v[e], o) : fmaxf(v[e], o);
    }
}
__device__ __forceinline__ void lstage2(float p[8], float q[8], int j8, bool keepmin,
                                        float* sp, float* st, int t)
{
    __syncthreads();
    float4* wp = (float4*)(sp + t * 8);
    float4* wq = (float4*)(st + t * 8);
    wp[0] = make_float4(p[0], p[1], p[2], p[3]);
    wp[1] = make_float4(p[4], p[5], p[6], p[7]);
    wq[0] = make_float4(q[0], q[1], q[2], q[3]);
    wq[1] = make_float4(q[4], q[5], q[6], q[7]);
    __syncthreads();
    int pt = t ^ j8;
    const float4* rp = (const float4*)(sp + pt * 8);
    const float4* rq = (const float4*)(st + pt * 8);
    float4 a = rp[0], bb = rp[1], c = rq[0], d = rq[1];
    float op[8] = {a.x, a.y, a.z, a.w, bb.x, bb.y, bb.z, bb.w};
    float oq[8] = {c.x, c.y, c.z, c.w, d.x, d.y, d.z, d.w};
    #pragma unroll
    for (int e = 0; e < 8; ++e) {
        p[e] = keepmin ? fminf(p[e], op[e]) : fmaxf(p[e], op[e]);
        q[e] = keepmin ? fminf(q[e], oq[e]) : fmaxf(q[e], oq[e]);
    }
}

__global__ __launch_bounds__(512) void k_loss(const float* __restrict__ bufB,
                                              const float* __restrict__ minmax,
                                              float* __restrict__ acc,
                                              unsigned* __restrict__ count,
                                              float* __restrict__ out)
{
    __shared__ float sp[4096];
    __shared__ float st[4096];
    __shared__ float rs[8];

    int t = threadIdx.x;
    int r = blockIdx.x & 7;
    int k = blockIdx.x >> 3;
    int b = r + 8 * (k >> 6);
    int w = k & 63;
    int wi = w >> 3, wj = w & 7;

    int i0 = t << 3;
    int y = wi * 64 + (i0 >> 6);
    int x = wj * 64 + (i0 & 63);

    float mnP = minmax[2 * b],        mxP = minmax[2 * b + 1];
    float mnT = minmax[2 * (16 + b)], mxT = minmax[2 * (16 + b) + 1];
    float sclP = 1.0f / (mxP - mnP + 1e-6f);
    float sclT = 1.0f / (mxT - mnT + 1e-6f);

    float p[8], q[8];
    {
        const float4* P4 = (const float4*)(bufB + (long)b * 262144 + y * 512 + x);
        const float4* T4 = (const float4*)(bufB + (long)(16 + b) * 262144 + y * 512 + x);
        float4 a = P4[0], bb = P4[1], c = T4[0], d = T4[1];
        p[0]=a.x; p[1]=a.y; p[2]=a.z; p[3]=a.w; p[4]=bb.x; p[5]=bb.y; p[6]=bb.z; p[7]=bb.w;
        q[0]=c.x; q[1]=c.y; q[2]=c.z; q[3]=c.w; q[4]=d.x;  q[5]=d.y;  q[6]=d.z;  q[7]=d.w;
        #pragma unroll
        for (int e = 0; e < 8; ++e) {
            p[e] = (p[e] - mnP) * sclP;
            q[e] = (q[e] - mnT) * sclT;
        }
    }

    bool u8 = ((t & 1) == 0);
    sort8(p, u8);
    sort8(q, u8);

    for (int kk = 16; kk <= 4096; kk <<= 1) {
        bool u = ((i0 & kk) == 0);
        for (int j = kk >> 1; j >= 8; j >>= 1) {
            bool l = ((i0 & j) == 0);
            bool keepmin = (u == l);
            int j8 = j >> 3;
            if (j8 < 64) {
                xstage(p, j8, keepmin);
                xstage(q, j8, keepmin);
            } else {
                lstage2(p, q, j8, keepmin, sp, st, t);
            }
        }
        merge8(p, u);
        merge8(q, u);
    }

    float s = 0.0f;
    #pragma unroll
    for (int e = 0; e < 8; ++e) { float d = p[e] - q[e]; s += d * d; }
    for (int o = 32; o > 0; o >>= 1) s += __shfl_down(s, o);
    if ((t & 63) == 0) rs[t >> 6] = s;
    __syncthreads();
    if (t == 0) {
        float tot = 0.0f;
        #pragma unroll
        for (int i = 0; i < 8; ++i) tot += rs[i];
        atomicAdd(acc, tot);
        __threadfence();
        unsigned done = atomicAdd(count, 1u);
        if (done == 1023u) {
            float total = atomicAdd(acc, 0.0f);
            float mean = total * (1.0f / 4194304.0f);
            out[0] = mean * 0.005f;
            out[1] = mean;
        }
    }
}

extern "C" void kernel_launch(void* const* d_in, const int* in_sizes, int n_in,
                              void* d_out, int out_size, void* d_ws, size_t ws_size,
                              hipStream_t stream)
{
    const float* pred = (const float*)d_in[0];
    const float* tgt  = (const float*)d_in[1];
    float* out = (float*)d_out;

    char* ws = (char*)d_ws;
    float* bufA     = (float*)ws;                     // 32 MB
    float* bufB     = (float*)(ws + (32ull << 20));   // 32 MB scratch
    float* minmax   = (float*)(ws + (64ull << 20));   // 64 floats
    float* acc      = minmax + 64;
    unsigned* count = (unsigned*)(acc + 1);

    k_init     <<<16 * 1024, 256, 0, stream>>>(pred, tgt, bufA, acc, count);
    k_sweep    <<<32, 1024, 0, stream>>>(bufA, bufB, minmax, 0);  // rows it1 -> A
    k_transpose<<<2048, 256, 0, stream>>>(bufA, bufB);            // A -> B
    k_sweep    <<<32, 1024, 0, stream>>>(bufB, bufA, minmax, 0);  // cols it1 -> B
    k_transpose<<<2048, 256, 0, stream>>>(bufB, bufA);            // B -> A
    k_sweep    <<<32, 1024, 0, stream>>>(bufA, bufB, minmax, 0);  // rows it2 -> A
    k_transpose<<<2048, 256, 0, stream>>>(bufA, bufB);            // A -> B
    k_sweep    <<<32, 1024, 0, stream>>>(bufB, bufA, minmax, 1);  // cols it2 -> B (+minmax)
    k_loss     <<<1024, 512, 0, stream>>>(bufB, minmax, acc, count, out);
}

// Round 9
// 457.411 us; speedup vs baseline: 1.7412x; 1.5216x over previous
//
#include <hip/hip_runtime.h>

#define BIGF 1e20f
#define VF   1e10f

constexpr float SQ2 = 1.41421356237309515f;  // fp32 0x3FB504F3, == jnp.sqrt(2.0) in f32

// ---------------------------------------------------------------------------
// DPP wave shifts
// ---------------------------------------------------------------------------
__device__ __forceinline__ float dpp_left(float x)
{
    int o = __builtin_amdgcn_update_dpp(0x60AD78ECu /*1e20f*/, __float_as_int(x),
                                        0x138, 0xF, 0xF, false);   // WAVE_SHR1
    return __int_as_float(o);
}
__device__ __forceinline__ float dpp_right(float x)
{
    int o = __builtin_amdgcn_update_dpp(0x60AD78ECu /*1e20f*/, __float_as_int(x),
                                        0x130, 0xF, 0xF, false);   // WAVE_SHL1
    return __int_as_float(o);
}

__device__ __forceinline__ void load_row8(const float* __restrict__ M, int r, int c0, float v[8])
{
    const float4* q = (const float4*)(M + ((long)r << 9) + c0);
    float4 a = q[0], b = q[1];
    v[0] = a.x; v[1] = a.y; v[2] = a.z; v[3] = a.w;
    v[4] = b.x; v[5] = b.y; v[6] = b.z; v[7] = b.w;
}
__device__ __forceinline__ void store_row8(float* __restrict__ M, int r, int c0, const float v[8])
{
    float4* q = (float4*)(M + ((long)r << 9) + c0);
    q[0] = make_float4(v[0], v[1], v[2], v[3]);
    q[1] = make_float4(v[4], v[5], v[6], v[7]);
}

// 3pt chamfer step: nv <- min(cur, p+1, min(neighbors)+SQ2)
__device__ __forceinline__ void step8(const float cur[8], const float p[8], float nv[8])
{
    float left  = dpp_left(p[7]);
    float right = dpp_right(p[0]);
    #pragma unroll
    for (int j = 0; j < 8; ++j) {
        float l  = (j == 0) ? left  : p[j - 1];
        float rr = (j == 7) ? right : p[j + 1];
        nv[j] = fminf(fminf(cur[j], p[j] + 1.0f), fminf(l, rr) + SQ2);
    }
}

// ---------------------------------------------------------------------------
// K1: binarize + channel max + dist init + scalar inits
// ---------------------------------------------------------------------------
__global__ __launch_bounds__(256) void k_init(const float* __restrict__ pred,
                                              const float* __restrict__ tgt,
                                              float* __restrict__ bufA,
                                              float* __restrict__ acc,
                                              unsigned* __restrict__ count,
                                              float* __restrict__ minmax)
{
    if (blockIdx.x == 0 && threadIdx.x == 0) { *acc = 0.0f; *count = 0u; }
    if (blockIdx.x == 0 && threadIdx.x < 64)
        minmax[threadIdx.x] = (threadIdx.x & 1) ? 0.0f : BIGF;   // [2m]=min slot, [2m+1]=max slot

    int r = blockIdx.x & 7;
    int k = blockIdx.x >> 3;
    int b = r + 8 * (k >> 10);
    int pix = (k & 1023) * 256 + threadIdx.x;
    long base = (long)b * 3 * 262144 + pix;

    float p0 = pred[base], p1 = pred[base + 262144], p2 = pred[base + 2 * 262144];
    bool fgP = ((p0 + 1.0f) * 0.5f >= 0.7f) ||
               ((p1 + 1.0f) * 0.5f >= 0.7f) ||
               ((p2 + 1.0f) * 0.5f >= 0.7f);

    float t0 = tgt[base], t1 = tgt[base + 262144], t2 = tgt[base + 2 * 262144];
    float mt = fmaxf(fmaxf(t0, t1), t2);

    bufA[(long)b * 262144 + pix]        = fgP ? 0.0f : VF;
    bufA[(long)(16 + b) * 262144 + pix] = VF * (1.0f - mt);
}

// ---------------------------------------------------------------------------
// K_p1d: phase-1 down. 512 WGs (m = bi>>4, block w = bi&15), 64 threads.
// Internal down-DT of rows a..a+31 (seed = raw row a); output last row -> Cb.
// ---------------------------------------------------------------------------
__global__ __launch_bounds__(64) void k_p1d(const float* __restrict__ X0,
                                            float* __restrict__ Cb)
{
    int bi = blockIdx.x, m = bi >> 4, w = bi & 15;
    const float* X = X0 + ((long)m << 18);
    int c0 = (int)threadIdx.x << 3, a = w << 5;
    float p[8]; load_row8(X, a, c0, p);
    float buf[4][8];
    #pragma unroll
    for (int k = 1; k <= 3; ++k) load_row8(X, a + k, c0, buf[k & 3]);
    #pragma unroll
    for (int i = 1; i < 32; ++i) {
        if (i + 3 < 32) load_row8(X, a + i + 3, c0, buf[(i + 3) & 3]);
        float nv[8]; step8(buf[i & 3], p, nv);
        #pragma unroll
        for (int j = 0; j < 8; ++j) p[j] = nv[j];
    }
    float4* o = (float4*)(Cb + m * 8192 + w * 512 + c0);
    o[0] = make_float4(p[0], p[1], p[2], p[3]);
    o[1] = make_float4(p[4], p[5], p[6], p[7]);
}

// ---------------------------------------------------------------------------
// combine: bwp[wdst] = min(bwp[wdst], cone32(bwp[wsrc]))  (round-8, verified)
// ---------------------------------------------------------------------------
__device__ __forceinline__ void combine(float* __restrict__ bwp, float* __restrict__ part,
                                        int wdst, int wsrc, int t, int wave, int lane,
                                        const float wreg[8])
{
    const float* bs = bwp + wsrc * 576;
    if (wave <= 8) {
        int base = lane * 8 + 8 * wave;
        float W[16];
        float4 W0 = *(const float4*)(bs + base);
        float4 W1 = *(const float4*)(bs + base + 4);
        W[0]=W0.x; W[1]=W0.y; W[2]=W0.z; W[3]=W0.w;
        W[4]=W1.x; W[5]=W1.y; W[6]=W1.z; W[7]=W1.w;
        float acc[8];
        if (wave < 8) {
            float4 W2 = *(const float4*)(bs + base + 8);
            float4 W3 = *(const float4*)(bs + base + 12);
            W[8]=W2.x; W[9]=W2.y; W[10]=W2.z; W[11]=W2.w;
            W[12]=W3.x; W[13]=W3.y; W[14]=W3.z; W[15]=W3.w;
            #pragma unroll
            for (int j = 0; j < 8; ++j) acc[j] = W[j] + wreg[0];
            #pragma unroll
            for (int dt = 1; dt < 8; ++dt)
                #pragma unroll
                for (int j = 0; j < 8; ++j)
                    acc[j] = fminf(acc[j], W[j + dt] + wreg[dt]);
        } else {               // Delta = +32 only
            #pragma unroll
            for (int j = 0; j < 8; ++j) acc[j] = W[j] + wreg[0];
        }
        float4* pp = (float4*)(part + wave * 512 + lane * 8);
        pp[0] = make_float4(acc[0], acc[1], acc[2], acc[3]);
        pp[1] = make_float4(acc[4], acc[5], acc[6], acc[7]);
    }
    __syncthreads();
    if (t < 512) {
        float r = bwp[wdst * 576 + 32 + t];
        #pragma unroll
        for (int p2 = 0; p2 < 9; ++p2) r = fminf(r, part[p2 * 512 + t]);
        bwp[wdst * 576 + 32 + t] = r;
    }
    __syncthreads();
}

// ---------------------------------------------------------------------------
// K_comb: 15 serial combines over Cb (in place). dir=+1 down, -1 up. 32 WGs.
// ---------------------------------------------------------------------------
__global__ __launch_bounds__(1024) void k_comb(float* __restrict__ Cb, int dir)
{
    __shared__ __align__(16) float bwp[16 * 576];
    __shared__ __align__(16) float part[9 * 512];
    __shared__ float wgt[72];
    int m = blockIdx.x, t = threadIdx.x, wave = t >> 6, lane = t & 63, c0 = lane << 3;
    float* Cm = Cb + m * 8192;

    bwp[wave * 576 + ((lane < 32) ? lane : lane + 512)] = BIGF;
    *(float4*)(bwp + wave * 576 + 32 + c0)     = *(const float4*)(Cm + wave * 512 + c0);
    *(float4*)(bwp + wave * 576 + 32 + c0 + 4) = *(const float4*)(Cm + wave * 512 + c0 + 4);
    if (t < 65) { int d = t - 32; int ad = d < 0 ? -d : d; wgt[t] = ad * SQ2 + (float)(32 - ad); }
    __syncthreads();
    float wreg[8];
    #pragma unroll
    for (int dt = 0; dt < 8; ++dt) wreg[dt] = BIGF;
    if (wave < 8) {
        #pragma unroll
        for (int dt = 0; dt < 8; ++dt) wreg[dt] = wgt[wave * 8 + dt];
    } else if (wave == 8) wreg[0] = wgt[64];

    #pragma unroll 1
    for (int i = 0; i < 15; ++i) {
        int w2 = (dir > 0) ? (1 + i) : (14 - i);
        combine(bwp, part, w2, w2 - dir, t, wave, lane, wreg);
    }
    *(float4*)(Cm + wave * 512 + c0)     = *(const float4*)(bwp + wave * 576 + 32 + c0);
    *(float4*)(Cm + wave * 512 + c0 + 4) = *(const float4*)(bwp + wave * 576 + 32 + c0 + 4);
}

// ---------------------------------------------------------------------------
// K_p3d1u: phase-3 down (seeded exact recurrence, write Y) + fused phase-1 up
// (re-reads its own freshly written rows; L2-hot). 512 WGs x 64.
// ---------------------------------------------------------------------------
__global__ __launch_bounds__(64) void k_p3d1u(const float* __restrict__ X0,
                                              float* __restrict__ Y0,
                                              const float* __restrict__ Cb,
                                              float* __restrict__ Db)
{
    int bi = blockIdx.x, m = bi >> 4, w = bi & 15;
    const float* X = X0 + ((long)m << 18);
    float* Y = Y0 + ((long)m << 18);
    int c0 = (int)threadIdx.x << 3, a = w << 5;
    float p[8], buf[4][8];

    if (w == 0) {
        load_row8(X, 0, c0, p);
        store_row8(Y, 0, c0, p);
        #pragma unroll
        for (int k = 1; k <= 3; ++k) load_row8(X, k, c0, buf[k & 3]);
        #pragma unroll
        for (int i = 1; i < 32; ++i) {
            if (i + 3 < 32) load_row8(X, i + 3, c0, buf[(i + 3) & 3]);
            float nv[8]; step8(buf[i & 3], p, nv);
            store_row8(Y, i, c0, nv);
            #pragma unroll
            for (int j = 0; j < 8; ++j) p[j] = nv[j];
        }
    } else {
        const float4* s = (const float4*)(Cb + m * 8192 + (w - 1) * 512 + c0);
        float4 s0 = s[0], s1 = s[1];
        p[0]=s0.x; p[1]=s0.y; p[2]=s0.z; p[3]=s0.w;
        p[4]=s1.x; p[5]=s1.y; p[6]=s1.z; p[7]=s1.w;
        #pragma unroll
        for (int k = 0; k < 3; ++k) load_row8(X, a + k, c0, buf[k & 3]);
        #pragma unroll
        for (int i = 0; i < 32; ++i) {
            if (i + 3 < 32) load_row8(X, a + i + 3, c0, buf[(i + 3) & 3]);
            float nv[8]; step8(buf[i & 3], p, nv);
            store_row8(Y, a + i, c0, nv);
            #pragma unroll
            for (int j = 0; j < 8; ++j) p[j] = nv[j];
        }
    }

    // fused phase-1 up: internal up-DT of the down-swept block; seed = row a+31 (=p)
    float q[8];
    #pragma unroll
    for (int j = 0; j < 8; ++j) q[j] = p[j];
    #pragma unroll
    for (int k = 1; k <= 3; ++k) load_row8(Y, a + 31 - k, c0, buf[k & 3]);
    #pragma unroll
    for (int i = 1; i < 32; ++i) {
        if (i + 3 < 32) load_row8(Y, a + 31 - (i + 3), c0, buf[(i + 3) & 3]);
        float nv[8]; step8(buf[i & 3], q, nv);
        #pragma unroll
        for (int j = 0; j < 8; ++j) q[j] = nv[j];
    }
    float4* o = (float4*)(Db + m * 8192 + w * 512 + c0);
    o[0] = make_float4(q[0], q[1], q[2], q[3]);
    o[1] = make_float4(q[4], q[5], q[6], q[7]);
}

// ---------------------------------------------------------------------------
// K_p3u: phase-3 up + fused TRANSPOSED write (two 16-row half-tiles in LDS,
// stride 516 => 2-way-free banks; 128B-contiguous output chunks) + minmax.
// ---------------------------------------------------------------------------
__device__ __forceinline__ void tile_store(float* tile, int h, int c0, const float v[8])
{
    float4* q = (float4*)(tile + h * 516 + c0);
    q[0] = make_float4(v[0], v[1], v[2], v[3]);
    q[1] = make_float4(v[4], v[5], v[6], v[7]);
}
__device__ __forceinline__ void half_out(const float* tile, float* __restrict__ Xo,
                                         int a2, int L)
{
    int g = L >> 2, j = (L & 3) << 2;           // 4 lanes per out-row, 16 rows/instr
    #pragma unroll
    for (int it = 0; it < 32; ++it) {
        int c = (it << 4) + g;
        float4 v = make_float4(tile[(j + 0) * 516 + c], tile[(j + 1) * 516 + c],
                               tile[(j + 2) * 516 + c], tile[(j + 3) * 516 + c]);
        *(float4*)(Xo + (long)c * 512 + a2 + j) = v;   // out[c][a2+j..a2+j+3]
    }
}

__global__ __launch_bounds__(64) void k_p3u(const float* __restrict__ Y0,
                                            float* __restrict__ Xo0,
                                            const float* __restrict__ Db,
                                            float* __restrict__ minmax,
                                            int final_pass)
{
    __shared__ __align__(16) float tile[16 * 516];
    int bi = blockIdx.x, m = bi >> 4, w = bi & 15;
    const float* Y = Y0 + ((long)m << 18);
    float* Xo = Xo0 + ((long)m << 18);
    int L = threadIdx.x, c0 = L << 3, a = w << 5;
    float p[8], buf[4][8];
    float mn = BIGF, mx = -BIGF;

    if (w == 15) {
        load_row8(Y, 511, c0, p);
        tile_store(tile, 15, c0, p);
        #pragma unroll
        for (int j = 0; j < 8; ++j) { mn = fminf(mn, p[j]); mx = fmaxf(mx, p[j]); }
        #pragma unroll
        for (int k = 1; k <= 3; ++k) load_row8(Y, 511 - k, c0, buf[k & 3]);
        #pragma unroll
        for (int i = 1; i < 16; ++i) {                       // rows 510..496 -> tile 14..0
            load_row8(Y, 511 - (i + 3), c0, buf[(i + 3) & 3]);
            float nv[8]; step8(buf[i & 3], p, nv);
            tile_store(tile, 15 - i, c0, nv);
            #pragma unroll
            for (int j = 0; j < 8; ++j) { p[j] = nv[j]; mn = fminf(mn, nv[j]); mx = fmaxf(mx, nv[j]); }
        }
        half_out(tile, Xo, a + 16, L);
        #pragma unroll
        for (int i = 16; i < 32; ++i) {                      // rows 495..480 -> tile 15..0
            if (i + 3 < 32) load_row8(Y, 511 - (i + 3), c0, buf[(i + 3) & 3]);
            float nv[8]; step8(buf[i & 3], p, nv);
            tile_store(tile, 31 - i, c0, nv);
            #pragma unroll
            for (int j = 0; j < 8; ++j) { p[j] = nv[j]; mn = fminf(mn, nv[j]); mx = fmaxf(mx, nv[j]); }
        }
        half_out(tile, Xo, a, L);
    } else {
        const float4* s = (const float4*)(Db + m * 8192 + (w + 1) * 512 + c0);
        float4 s0 = s[0], s1 = s[1];
        p[0]=s0.x; p[1]=s0.y; p[2]=s0.z; p[3]=s0.w;
        p[4]=s1.x; p[5]=s1.y; p[6]=s1.z; p[7]=s1.w;
        #pragma unroll
        for (int k = 0; k < 3; ++k) load_row8(Y, a + 31 - k, c0, buf[k & 3]);
        #pragma unroll
        for (int i = 0; i < 16; ++i) {                       // rows a+31..a+16 -> tile 15..0
            load_row8(Y, a + 31 - (i + 3), c0, buf[(i + 3) & 3]);
            float nv[8]; step8(buf[i & 3], p, nv);
            tile_store(tile, 15 - i, c0, nv);
            #pragma unroll
            for (int j = 0; j < 8; ++j) { p[j] = nv[j]; mn = fminf(mn, nv[j]); mx = fmaxf(mx, nv[j]); }
        }
        half_out(tile, Xo, a + 16, L);
        #pragma unroll
        for (int i = 16; i < 32; ++i) {                      // rows a+15..a -> tile 15..0
            if (i + 3 < 32) load_row8(Y, a + 31 - (i + 3), c0, buf[(i + 3) & 3]);
            float nv[8]; step8(buf[i & 3], p, nv);
            tile_store(tile, 31 - i, c0, nv);
            #pragma unroll
            for (int j = 0; j < 8; ++j) { p[j] = nv[j]; mn = fminf(mn, nv[j]); mx = fmaxf(mx, nv[j]); }
        }
        half_out(tile, Xo, a, L);
    }

    if (final_pass) {
        for (int o = 32; o > 0; o >>= 1) {
            mn = fminf(mn, __shfl_down(mn, o));
            mx = fmaxf(mx, __shfl_down(mx, o));
        }
        if (L == 0) {       // distances >= 0: float order == int-bit order
            atomicMin((int*)(minmax + 2 * m),     __float_as_int(mn));
            atomicMax((int*)(minmax + 2 * m + 1), __float_as_int(mx));
        }
    }
}

// ---------------------------------------------------------------------------
// K_loss: register-blocked bitonic sort (8/thread) + MSE + fused finalize.
// ---------------------------------------------------------------------------
__device__ __forceinline__ void ce(float& a, float& b, bool up)
{
    float lo = fminf(a, b), hi = fmaxf(a, b);
    a = up ? lo : hi;
    b = up ? hi : lo;
}
__device__ __forceinline__ void merge8(float v[8], bool up)
{
    ce(v[0], v[4], up); ce(v[1], v[5], up); ce(v[2], v[6], up); ce(v[3], v[7], up);
    ce(v[0], v[2], up); ce(v[1], v[3], up); ce(v[4], v[6], up); ce(v[5], v[7], up);
    ce(v[0], v[1], up); ce(v[2], v[3], up); ce(v[4], v[5], up); ce(v[6], v[7], up);
}
__device__ __forceinline__ void sort8(float v[8], bool u8)
{
    ce(v[0], v[1], true);  ce(v[2], v[3], false);
    ce(v[4], v[5], true);  ce(v[6], v[7], false);
    ce(v[0], v[2], true);  ce(v[1], v[3], true);
    ce(v[4], v[6], false); ce(v[5], v[7], false);
    ce(v[0], v[1], true);  ce(v[2], v[3], true);
    ce(v[4], v[5], false); ce(v[6], v[7], false);
    merge8(v, u8);
}
__device__ __forceinline__ void xstage(float v[8], int j8, bool keepmin)
{
    #pragma unroll
    for (int e = 0; e < 8; ++e) {
        float o = __shfl_xor(v[e], j8);
        v[e] = keepmin ? fminf(v[e], o) : fmaxf(v[e], o);
    }
}
__device__ __forceinline__ void lstage2(float p[8], float q[8], int j8, bool keepmin,
                                        float* sp, float* st, int t)
{
    __syncthreads();
    float4* wp = (float4*)(sp + t * 8);
    float4* wq = (float4*)(st + t * 8);
    wp[0] = make_float4(p[0], p[1], p[2], p[3]);
    wp[1] = make_float4(p[4], p[5], p[6], p[7]);
    wq[0] = make_float4(q[0], q[1], q[2], q[3]);
    wq[1] = make_float4(q[4], q[5], q[6], q[7]);
    __syncthreads();
    int pt = t ^ j8;
    const float4* rp = (const float4*)(sp + pt * 8);
    const float4* rq = (const float4*)(st + pt * 8);
    float4 a = rp[0], bb = rp[1], c = rq[0], d = rq[1];
    float op[8] = {a.x, a.y, a.z, a.w, bb.x, bb.y, bb.z, bb.w};
    float oq[8] = {c.x, c.y, c.z, c.w, d.x, d.y, d.z, d.w};
    #pragma unroll
    for (int e = 0; e < 8; ++e) {
        p[e] = keepmin ? fminf(p[e], op[e]) : fmaxf(p[e], op[e]);
        q[e] = keepmin ? fminf(q[e], oq[e]) : fmaxf(q[e], oq[e]);
    }
}

__global__ __launch_bounds__(512) void k_loss(const float* __restrict__ bufB,
                                              const float* __restrict__ minmax,
                                              float* __restrict__ acc,
                                              unsigned* __restrict__ count,
                                              float* __restrict__ out)
{
    __shared__ float sp[4096];
    __shared__ float st[4096];
    __shared__ float rs[8];

    int t = threadIdx.x;
    int r = blockIdx.x & 7;
    int k = blockIdx.x >> 3;
    int b = r + 8 * (k >> 6);
    int w = k & 63;
    int wi = w >> 3, wj = w & 7;

    int i0 = t << 3;
    int y = wi * 64 + (i0 >> 6);
    int x = wj * 64 + (i0 & 63);

    float mnP = minmax[2 * b],        mxP = minmax[2 * b + 1];
    float mnT = minmax[2 * (16 + b)], mxT = minmax[2 * (16 + b) + 1];
    float sclP = 1.0f / (mxP - mnP + 1e-6f);
    float sclT = 1.0f / (mxT - mnT + 1e-6f);

    float p[8], q[8];
    {
        const float4* P4 = (const float4*)(bufB + (long)b * 262144 + y * 512 + x);
        const float4* T4 = (const float4*)(bufB + (long)(16 + b) * 262144 + y * 512 + x);
        float4 a = P4[0], bb = P4[1], c = T4[0], d = T4[1];
        p[0]=a.x; p[1]=a.y; p[2]=a.z; p[3]=a.w; p[4]=bb.x; p[5]=bb.y; p[6]=bb.z; p[7]=bb.w;
        q[0]=c.x; q[1]=c.y; q[2]=c.z; q[3]=c.w; q[4]=d.x;  q[5]=d.y;  q[6]=d.z;  q[7]=d.w;
        #pragma unroll
        for (int e = 0; e < 8; ++e) {
            p[e] = (p[e] - mnP) * sclP;
            q[e] = (q[e] - mnT) * sclT;
        }
    }

    bool u8 = ((t & 1) == 0);
    sort8(p, u8);
    sort8(q, u8);

    for (int kk = 16; kk <= 4096; kk <<= 1) {
        bool u = ((i0 & kk) == 0);
        for (int j = kk >> 1; j >= 8; j >>= 1) {
            bool l = ((i0 & j) == 0);
            bool keepmin = (u == l);
            int j8 = j >> 3;
            if (j8 < 64) {
                xstage(p, j8, keepmin);
                xstage(q, j8, keepmin);
            } else {
                lstage2(p, q, j8, keepmin, sp, st, t);
            }
        }
        merge8(p, u);
        merge8(q, u);
    }

    float s = 0.0f;
    #pragma unroll
    for (int e = 0; e < 8; ++e) { float d = p[e] - q[e]; s += d * d; }
    for (int o = 32; o > 0; o >>= 1) s += __shfl_down(s, o);
    if ((t & 63) == 0) rs[t >> 6] = s;
    __syncthreads();
    if (t == 0) {
        float tot = 0.0f;
        #pragma unroll
        for (int i = 0; i < 8; ++i) tot += rs[i];
        atomicAdd(acc, tot);
        __threadfence();
        unsigned done = atomicAdd(count, 1u);
        if (done == 1023u) {
            float total = atomicAdd(acc, 0.0f);
            float mean = total * (1.0f / 4194304.0f);
            out[0] = mean * 0.005f;
            out[1] = mean;
        }
    }
}

extern "C" void kernel_launch(void* const* d_in, const int* in_sizes, int n_in,
                              void* d_out, int out_size, void* d_ws, size_t ws_size,
                              hipStream_t stream)
{
    const float* pred = (const float*)d_in[0];
    const float* tgt  = (const float*)d_in[1];
    float* out = (float*)d_out;

    char* ws = (char*)d_ws;
    float* bufA     = (float*)ws;                       // 32 MB
    float* bufB     = (float*)(ws + (32ull << 20));     // 32 MB
    float* Cb       = (float*)(ws + (64ull << 20));     // 1 MB boundary rows (down)
    float* Db       = (float*)(ws + (65ull << 20));     // 1 MB boundary rows (up)
    float* minmax   = (float*)(ws + (66ull << 20));     // 64 floats
    float* acc      = minmax + 64;
    unsigned* count = (unsigned*)(acc + 1);

    k_init<<<16 * 1024, 256, 0, stream>>>(pred, tgt, bufA, acc, count, minmax);

    for (int s = 0; s < 4; ++s) {
        k_p1d  <<<512,   64, 0, stream>>>(bufA, Cb);
        k_comb <<< 32, 1024, 0, stream>>>(Cb, +1);
        k_p3d1u<<<512,   64, 0, stream>>>(bufA, bufB, Cb, Db);
        k_comb <<< 32, 1024, 0, stream>>>(Db, -1);
        k_p3u  <<<512,   64, 0, stream>>>(bufB, bufA, Db, minmax, s == 3 ? 1 : 0);
    }

    k_loss<<<1024, 512, 0, stream>>>(bufA, minmax, acc, count, out);
}

// Round 10
// 409.540 us; speedup vs baseline: 1.9447x; 1.1169x over previous
//
#include <hip/hip_runtime.h>

#define BIGF 1e20f
#define VF   1e10f

constexpr float SQ2 = 1.41421356237309515f;  // fp32 0x3FB504F3, == jnp.sqrt(2.0) in f32

// ---------------------------------------------------------------------------
// DPP helpers
// ---------------------------------------------------------------------------
__device__ __forceinline__ float dpp_left(float x)
{
    int o = __builtin_amdgcn_update_dpp(0x60AD78ECu /*1e20f*/, __float_as_int(x),
                                        0x138, 0xF, 0xF, false);   // WAVE_SHR1
    return __int_as_float(o);
}
__device__ __forceinline__ float dpp_right(float x)
{
    int o = __builtin_amdgcn_update_dpp(0x60AD78ECu /*1e20f*/, __float_as_int(x),
                                        0x130, 0xF, 0xF, false);   // WAVE_SHL1
    return __int_as_float(o);
}
template<int CTRL>
__device__ __forceinline__ float qdpp(float x)   // quad_perm xor patterns
{
    return __int_as_float(__builtin_amdgcn_update_dpp(0, __float_as_int(x),
                                                      CTRL, 0xF, 0xF, true));
}
__device__ __forceinline__ float fmed3(float a, float b, float c)
{
    return __builtin_amdgcn_fmed3f(a, b, c);
}

__device__ __forceinline__ void load_row8(const float* __restrict__ M, int r, int c0, float v[8])
{
    const float4* q = (const float4*)(M + ((long)r << 9) + c0);
    float4 a = q[0], b = q[1];
    v[0] = a.x; v[1] = a.y; v[2] = a.z; v[3] = a.w;
    v[4] = b.x; v[5] = b.y; v[6] = b.z; v[7] = b.w;
}
__device__ __forceinline__ void store_row8(float* __restrict__ M, int r, int c0, const float v[8])
{
    float4* q = (float4*)(M + ((long)r << 9) + c0);
    q[0] = make_float4(v[0], v[1], v[2], v[3]);
    q[1] = make_float4(v[4], v[5], v[6], v[7]);
}

// 3pt chamfer step: nv <- min(cur, p+1, min(neighbors)+SQ2)
__device__ __forceinline__ void step8(const float cur[8], const float p[8], float nv[8])
{
    float left  = dpp_left(p[7]);
    float right = dpp_right(p[0]);
    #pragma unroll
    for (int j = 0; j < 8; ++j) {
        float l  = (j == 0) ? left  : p[j - 1];
        float rr = (j == 7) ? right : p[j + 1];
        nv[j] = fminf(fminf(cur[j], p[j] + 1.0f), fminf(l, rr) + SQ2);
    }
}

// ---------------------------------------------------------------------------
// K1: binarize + channel max + dist init + scalar inits
// ---------------------------------------------------------------------------
__global__ __launch_bounds__(256) void k_init(const float* __restrict__ pred,
                                              const float* __restrict__ tgt,
                                              float* __restrict__ bufA,
                                              float* __restrict__ acc,
                                              unsigned* __restrict__ count,
                                              float* __restrict__ minmax)
{
    if (blockIdx.x == 0 && threadIdx.x == 0) { *acc = 0.0f; *count = 0u; }
    if (blockIdx.x == 0 && threadIdx.x < 64)
        minmax[threadIdx.x] = (threadIdx.x & 1) ? 0.0f : BIGF;

    int r = blockIdx.x & 7;
    int k = blockIdx.x >> 3;
    int b = r + 8 * (k >> 10);
    int pix = (k & 1023) * 256 + threadIdx.x;
    long base = (long)b * 3 * 262144 + pix;

    float p0 = pred[base], p1 = pred[base + 262144], p2 = pred[base + 2 * 262144];
    bool fgP = ((p0 + 1.0f) * 0.5f >= 0.7f) ||
               ((p1 + 1.0f) * 0.5f >= 0.7f) ||
               ((p2 + 1.0f) * 0.5f >= 0.7f);

    float t0 = tgt[base], t1 = tgt[base + 262144], t2 = tgt[base + 2 * 262144];
    float mt = fmaxf(fmaxf(t0, t1), t2);

    bufA[(long)b * 262144 + pix]        = fgP ? 0.0f : VF;
    bufA[(long)(16 + b) * 262144 + pix] = VF * (1.0f - mt);
}

// ---------------------------------------------------------------------------
// K_p1d: phase-1 down. 512 WGs (m = bi>>4, block w = bi&15), 64 threads.
// ---------------------------------------------------------------------------
__global__ __launch_bounds__(64) void k_p1d(const float* __restrict__ X0,
                                            float* __restrict__ Cb)
{
    int bi = blockIdx.x, m = bi >> 4, w = bi & 15;
    const float* X = X0 + ((long)m << 18);
    int c0 = (int)threadIdx.x << 3, a = w << 5;
    float p[8]; load_row8(X, a, c0, p);
    float buf[4][8];
    #pragma unroll
    for (int k = 1; k <= 3; ++k) load_row8(X, a + k, c0, buf[k & 3]);
    #pragma unroll
    for (int i = 1; i < 32; ++i) {
        if (i + 3 < 32) load_row8(X, a + i + 3, c0, buf[(i + 3) & 3]);
        float nv[8]; step8(buf[i & 3], p, nv);
        #pragma unroll
        for (int j = 0; j < 8; ++j) p[j] = nv[j];
    }
    float4* o = (float4*)(Cb + m * 8192 + w * 512 + c0);
    o[0] = make_float4(p[0], p[1], p[2], p[3]);
    o[1] = make_float4(p[4], p[5], p[6], p[7]);
}

// ---------------------------------------------------------------------------
// combine: bwp[wdst] = min(bwp[wdst], cone32(bwp[wsrc]))  (verified exact)
// ---------------------------------------------------------------------------
__device__ __forceinline__ void combine(float* __restrict__ bwp, float* __restrict__ part,
                                        int wdst, int wsrc, int t, int wave, int lane,
                                        const float wreg[8])
{
    const float* bs = bwp + wsrc * 576;
    if (wave <= 8) {
        int base = lane * 8 + 8 * wave;
        float W[16];
        float4 W0 = *(const float4*)(bs + base);
        float4 W1 = *(const float4*)(bs + base + 4);
        W[0]=W0.x; W[1]=W0.y; W[2]=W0.z; W[3]=W0.w;
        W[4]=W1.x; W[5]=W1.y; W[6]=W1.z; W[7]=W1.w;
        float acc[8];
        if (wave < 8) {
            float4 W2 = *(const float4*)(bs + base + 8);
            float4 W3 = *(const float4*)(bs + base + 12);
            W[8]=W2.x; W[9]=W2.y; W[10]=W2.z; W[11]=W2.w;
            W[12]=W3.x; W[13]=W3.y; W[14]=W3.z; W[15]=W3.w;
            #pragma unroll
            for (int j = 0; j < 8; ++j) acc[j] = W[j] + wreg[0];
            #pragma unroll
            for (int dt = 1; dt < 8; ++dt)
                #pragma unroll
                for (int j = 0; j < 8; ++j)
                    acc[j] = fminf(acc[j], W[j + dt] + wreg[dt]);
        } else {
            #pragma unroll
            for (int j = 0; j < 8; ++j) acc[j] = W[j] + wreg[0];
        }
        float4* pp = (float4*)(part + wave * 512 + lane * 8);
        pp[0] = make_float4(acc[0], acc[1], acc[2], acc[3]);
        pp[1] = make_float4(acc[4], acc[5], acc[6], acc[7]);
    }
    __syncthreads();
    if (t < 512) {
        float r = bwp[wdst * 576 + 32 + t];
        #pragma unroll
        for (int p2 = 0; p2 < 9; ++p2) r = fminf(r, part[p2 * 512 + t]);
        bwp[wdst * 576 + 32 + t] = r;
    }
    __syncthreads();
}

// ---------------------------------------------------------------------------
// K_comb: 15 serial combines over Cb (in place). dir=+1 down, -1 up. 32 WGs.
// ---------------------------------------------------------------------------
__global__ __launch_bounds__(1024) void k_comb(float* __restrict__ Cb, int dir)
{
    __shared__ __align__(16) float bwp[16 * 576];
    __shared__ __align__(16) float part[9 * 512];
    __shared__ float wgt[72];
    int m = blockIdx.x, t = threadIdx.x, wave = t >> 6, lane = t & 63, c0 = lane << 3;
    float* Cm = Cb + m * 8192;

    bwp[wave * 576 + ((lane < 32) ? lane : lane + 512)] = BIGF;
    *(float4*)(bwp + wave * 576 + 32 + c0)     = *(const float4*)(Cm + wave * 512 + c0);
    *(float4*)(bwp + wave * 576 + 32 + c0 + 4) = *(const float4*)(Cm + wave * 512 + c0 + 4);
    if (t < 65) { int d = t - 32; int ad = d < 0 ? -d : d; wgt[t] = ad * SQ2 + (float)(32 - ad); }
    __syncthreads();
    float wreg[8];
    #pragma unroll
    for (int dt = 0; dt < 8; ++dt) wreg[dt] = BIGF;
    if (wave < 8) {
        #pragma unroll
        for (int dt = 0; dt < 8; ++dt) wreg[dt] = wgt[wave * 8 + dt];
    } else if (wave == 8) wreg[0] = wgt[64];

    #pragma unroll 1
    for (int i = 0; i < 15; ++i) {
        int w2 = (dir > 0) ? (1 + i) : (14 - i);
        combine(bwp, part, w2, w2 - dir, t, wave, lane, wreg);
    }
    *(float4*)(Cm + wave * 512 + c0)     = *(const float4*)(bwp + wave * 576 + 32 + c0);
    *(float4*)(Cm + wave * 512 + c0 + 4) = *(const float4*)(bwp + wave * 576 + 32 + c0 + 4);
}

// ---------------------------------------------------------------------------
// K_p3d1u: phase-3 down (seeded exact recurrence, write Y) + fused phase-1 up
// reading its own rows from a 62KB LDS stash (lane-interleaved float4 slots,
// conflict-free) instead of re-reading Y through L2. 512 WGs x 64.
// ---------------------------------------------------------------------------
__global__ __launch_bounds__(64) void k_p3d1u(const float* __restrict__ X0,
                                              float* __restrict__ Y0,
                                              const float* __restrict__ Cb,
                                              float* __restrict__ Db)
{
    __shared__ __align__(16) float stash[31 * 512];   // rows 0..30 only (row31 in regs)
    int bi = blockIdx.x, m = bi >> 4, w = bi & 15;
    const float* X = X0 + ((long)m << 18);
    float* Y = Y0 + ((long)m << 18);
    const int L = threadIdx.x;
    int c0 = L << 3, a = w << 5;
    float p[8], buf[4][8];

    if (w == 0) {
        load_row8(X, 0, c0, p);
        store_row8(Y, 0, c0, p);
        *(float4*)(stash + 0 * 512 + L * 4)       = make_float4(p[0], p[1], p[2], p[3]);
        *(float4*)(stash + 0 * 512 + 256 + L * 4) = make_float4(p[4], p[5], p[6], p[7]);
        #pragma unroll
        for (int k = 1; k <= 3; ++k) load_row8(X, k, c0, buf[k & 3]);
        #pragma unroll
        for (int i = 1; i < 32; ++i) {
            if (i + 3 < 32) load_row8(X, i + 3, c0, buf[(i + 3) & 3]);
            float nv[8]; step8(buf[i & 3], p, nv);
            store_row8(Y, i, c0, nv);
            if (i < 31) {
                *(float4*)(stash + i * 512 + L * 4)       = make_float4(nv[0], nv[1], nv[2], nv[3]);
                *(float4*)(stash + i * 512 + 256 + L * 4) = make_float4(nv[4], nv[5], nv[6], nv[7]);
            }
            #pragma unroll
            for (int j = 0; j < 8; ++j) p[j] = nv[j];
        }
    } else {
        const float4* s = (const float4*)(Cb + m * 8192 + (w - 1) * 512 + c0);
        float4 s0 = s[0], s1 = s[1];
        p[0]=s0.x; p[1]=s0.y; p[2]=s0.z; p[3]=s0.w;
        p[4]=s1.x; p[5]=s1.y; p[6]=s1.z; p[7]=s1.w;
        #pragma unroll
        for (int k = 0; k < 3; ++k) load_row8(X, a + k, c0, buf[k & 3]);
        #pragma unroll
        for (int i = 0; i < 32; ++i) {
            if (i + 3 < 32) load_row8(X, a + i + 3, c0, buf[(i + 3) & 3]);
            float nv[8]; step8(buf[i & 3], p, nv);
            store_row8(Y, a + i, c0, nv);
            if (i < 31) {
                *(float4*)(stash + i * 512 + L * 4)       = make_float4(nv[0], nv[1], nv[2], nv[3]);
                *(float4*)(stash + i * 512 + 256 + L * 4) = make_float4(nv[4], nv[5], nv[6], nv[7]);
            }
            #pragma unroll
            for (int j = 0; j < 8; ++j) p[j] = nv[j];
        }
    }

    // fused phase-1 up from LDS stash; seed = row a+31 (in p)
    float q[8], cur[8];
    #pragma unroll
    for (int j = 0; j < 8; ++j) q[j] = p[j];
    {
        float4 x0 = *(const float4*)(stash + 30 * 512 + L * 4);
        float4 x1 = *(const float4*)(stash + 30 * 512 + 256 + L * 4);
        cur[0]=x0.x; cur[1]=x0.y; cur[2]=x0.z; cur[3]=x0.w;
        cur[4]=x1.x; cur[5]=x1.y; cur[6]=x1.z; cur[7]=x1.w;
    }
    #pragma unroll
    for (int i = 1; i < 32; ++i) {
        float nxt[8];
        if (i < 31) {
            float4 x0 = *(const float4*)(stash + (30 - i) * 512 + L * 4);
            float4 x1 = *(const float4*)(stash + (30 - i) * 512 + 256 + L * 4);
            nxt[0]=x0.x; nxt[1]=x0.y; nxt[2]=x0.z; nxt[3]=x0.w;
            nxt[4]=x1.x; nxt[5]=x1.y; nxt[6]=x1.z; nxt[7]=x1.w;
        }
        float nv[8]; step8(cur, q, nv);
        #pragma unroll
        for (int j = 0; j < 8; ++j) q[j] = nv[j];
        if (i < 31) {
            #pragma unroll
            for (int j = 0; j < 8; ++j) cur[j] = nxt[j];
        }
    }
    float4* o = (float4*)(Db + m * 8192 + w * 512 + c0);
    o[0] = make_float4(q[0], q[1], q[2], q[3]);
    o[1] = make_float4(q[4], q[5], q[6], q[7]);
}

// ---------------------------------------------------------------------------
// K_p3u: phase-3 up + fused TRANSPOSED write + minmax.  (round-9, verified)
// ---------------------------------------------------------------------------
__device__ __forceinline__ void tile_store(float* tile, int h, int c0, const float v[8])
{
    float4* q = (float4*)(tile + h * 516 + c0);
    q[0] = make_float4(v[0], v[1], v[2], v[3]);
    q[1] = make_float4(v[4], v[5], v[6], v[7]);
}
__device__ __forceinline__ void half_out(const float* tile, float* __restrict__ Xo,
                                         int a2, int L)
{
    int g = L >> 2, j = (L & 3) << 2;
    #pragma unroll
    for (int it = 0; it < 32; ++it) {
        int c = (it << 4) + g;
        float4 v = make_float4(tile[(j + 0) * 516 + c], tile[(j + 1) * 516 + c],
                               tile[(j + 2) * 516 + c], tile[(j + 3) * 516 + c]);
        *(float4*)(Xo + (long)c * 512 + a2 + j) = v;
    }
}

__global__ __launch_bounds__(64) void k_p3u(const float* __restrict__ Y0,
                                            float* __restrict__ Xo0,
                                            const float* __restrict__ Db,
                                            float* __restrict__ minmax,
                                            int final_pass)
{
    __shared__ __align__(16) float tile[16 * 516];
    int bi = blockIdx.x, m = bi >> 4, w = bi & 15;
    const float* Y = Y0 + ((long)m << 18);
    float* Xo = Xo0 + ((long)m << 18);
    int L = threadIdx.x, c0 = L << 3, a = w << 5;
    float p[8], buf[4][8];
    float mn = BIGF, mx = -BIGF;

    if (w == 15) {
        load_row8(Y, 511, c0, p);
        tile_store(tile, 15, c0, p);
        #pragma unroll
        for (int j = 0; j < 8; ++j) { mn = fminf(mn, p[j]); mx = fmaxf(mx, p[j]); }
        #pragma unroll
        for (int k = 1; k <= 3; ++k) load_row8(Y, 511 - k, c0, buf[k & 3]);
        #pragma unroll
        for (int i = 1; i < 16; ++i) {
            load_row8(Y, 511 - (i + 3), c0, buf[(i + 3) & 3]);
            float nv[8]; step8(buf[i & 3], p, nv);
            tile_store(tile, 15 - i, c0, nv);
            #pragma unroll
            for (int j = 0; j < 8; ++j) { p[j] = nv[j]; mn = fminf(mn, nv[j]); mx = fmaxf(mx, nv[j]); }
        }
        half_out(tile, Xo, a + 16, L);
        #pragma unroll
        for (int i = 16; i < 32; ++i) {
            if (i + 3 < 32) load_row8(Y, 511 - (i + 3), c0, buf[(i + 3) & 3]);
            float nv[8]; step8(buf[i & 3], p, nv);
            tile_store(tile, 31 - i, c0, nv);
            #pragma unroll
            for (int j = 0; j < 8; ++j) { p[j] = nv[j]; mn = fminf(mn, nv[j]); mx = fmaxf(mx, nv[j]); }
        }
        half_out(tile, Xo, a, L);
    } else {
        const float4* s = (const float4*)(Db + m * 8192 + (w + 1) * 512 + c0);
        float4 s0 = s[0], s1 = s[1];
        p[0]=s0.x; p[1]=s0.y; p[2]=s0.z; p[3]=s0.w;
        p[4]=s1.x; p[5]=s1.y; p[6]=s1.z; p[7]=s1.w;
        #pragma unroll
        for (int k = 0; k < 3; ++k) load_row8(Y, a + 31 - k, c0, buf[k & 3]);
        #pragma unroll
        for (int i = 0; i < 16; ++i) {
            load_row8(Y, a + 31 - (i + 3), c0, buf[(i + 3) & 3]);
            float nv[8]; step8(buf[i & 3], p, nv);
            tile_store(tile, 15 - i, c0, nv);
            #pragma unroll
            for (int j = 0; j < 8; ++j) { p[j] = nv[j]; mn = fminf(mn, nv[j]); mx = fmaxf(mx, nv[j]); }
        }
        half_out(tile, Xo, a + 16, L);
        #pragma unroll
        for (int i = 16; i < 32; ++i) {
            if (i + 3 < 32) load_row8(Y, a + 31 - (i + 3), c0, buf[(i + 3) & 3]);
            float nv[8]; step8(buf[i & 3], p, nv);
            tile_store(tile, 31 - i, c0, nv);
            #pragma unroll
            for (int j = 0; j < 8; ++j) { p[j] = nv[j]; mn = fminf(mn, nv[j]); mx = fmaxf(mx, nv[j]); }
        }
        half_out(tile, Xo, a, L);
    }

    if (final_pass) {
        for (int o = 32; o > 0; o >>= 1) {
            mn = fminf(mn, __shfl_down(mn, o));
            mx = fmaxf(mx, __shfl_down(mx, o));
        }
        if (L == 0) {
            atomicMin((int*)(minmax + 2 * m),     __float_as_int(mn));
            atomicMax((int*)(minmax + 2 * m + 1), __float_as_int(mx));
        }
    }
}

// ---------------------------------------------------------------------------
// K_loss: NORMALIZED bitonic sort (all comparators min-low) with med3 trick.
// 8 elems/thread; reversal substages partner i^(k-1); DPP for xor masks 1,2,3.
// ---------------------------------------------------------------------------
__device__ __forceinline__ void cex(float& lo, float& hi)
{
    float l = fminf(lo, hi);
    hi = fmaxf(lo, hi);
    lo = l;
}
__device__ __forceinline__ void merge8asc(float v[8])
{
    cex(v[0],v[4]); cex(v[1],v[5]); cex(v[2],v[6]); cex(v[3],v[7]);
    cex(v[0],v[2]); cex(v[1],v[3]); cex(v[4],v[6]); cex(v[5],v[7]);
    cex(v[0],v[1]); cex(v[2],v[3]); cex(v[4],v[5]); cex(v[6],v[7]);
}
__device__ __forceinline__ void sort8asc(float v[8])
{
    cex(v[0],v[1]); cex(v[2],v[3]); cex(v[4],v[5]); cex(v[6],v[7]);   // k=2
    cex(v[0],v[3]); cex(v[1],v[2]); cex(v[4],v[7]); cex(v[5],v[6]);   // k=4 rev
    cex(v[0],v[1]); cex(v[2],v[3]); cex(v[4],v[5]); cex(v[6],v[7]);   // k=4 j=1
    cex(v[0],v[7]); cex(v[1],v[6]); cex(v[2],v[5]); cex(v[3],v[4]);   // k=8 rev
    cex(v[0],v[2]); cex(v[1],v[3]); cex(v[4],v[6]); cex(v[5],v[7]);   // j=2
    cex(v[0],v[1]); cex(v[2],v[3]); cex(v[4],v[5]); cex(v[6],v[7]);   // j=1
}
__device__ __forceinline__ void xshfl(float v[8], int j8, float sel)
{
    #pragma unroll
    for (int e = 0; e < 8; ++e) {
        float o = __shfl_xor(v[e], j8);
        v[e] = fmed3(v[e], o, sel);
    }
}
template<int CTRL>
__device__ __forceinline__ void xdpp(float v[8], float sel)
{
    #pragma unroll
    for (int e = 0; e < 8; ++e) {
        float o = qdpp<CTRL>(v[e]);
        v[e] = fmed3(v[e], o, sel);
    }
}
__device__ __forceinline__ void rshfl(float v[8], int tmask, float sel)
{
    float o[8];
    #pragma unroll
    for (int e = 0; e < 8; ++e) o[e] = __shfl_xor(v[7 - e], tmask);
    #pragma unroll
    for (int e = 0; e < 8; ++e) v[e] = fmed3(v[e], o[e], sel);
}
template<int CTRL>
__device__ __forceinline__ void rdpp(float v[8], float sel)
{
    float o[8];
    #pragma unroll
    for (int e = 0; e < 8; ++e) o[e] = qdpp<CTRL>(v[7 - e]);
    #pragma unroll
    for (int e = 0; e < 8; ++e) v[e] = fmed3(v[e], o[e], sel);
}
__device__ __forceinline__ void lstage(float p[8], float q[8], int tmask, float sel, bool rev,
                                       float* sp, float* st, int t)
{
    __syncthreads();
    float4* wp = (float4*)(sp + t * 8);
    float4* wq = (float4*)(st + t * 8);
    wp[0] = make_float4(p[0], p[1], p[2], p[3]);
    wp[1] = make_float4(p[4], p[5], p[6], p[7]);
    wq[0] = make_float4(q[0], q[1], q[2], q[3]);
    wq[1] = make_float4(q[4], q[5], q[6], q[7]);
    __syncthreads();
    int pt = t ^ tmask;
    const float4* rp = (const float4*)(sp + pt * 8);
    const float4* rq = (const float4*)(st + pt * 8);
    float4 a = rp[0], bb = rp[1], c = rq[0], d = rq[1];
    float op[8] = {a.x,a.y,a.z,a.w,bb.x,bb.y,bb.z,bb.w};
    float oq[8] = {c.x,c.y,c.z,c.w,d.x,d.y,d.z,d.w};
    if (rev) {
        #pragma unroll
        for (int e = 0; e < 8; ++e) {
            p[e] = fmed3(p[e], op[7 - e], sel);
            q[e] = fmed3(q[e], oq[7 - e], sel);
        }
    } else {
        #pragma unroll
        for (int e = 0; e < 8; ++e) {
            p[e] = fmed3(p[e], op[e], sel);
            q[e] = fmed3(q[e], oq[e], sel);
        }
    }
}

__global__ __launch_bounds__(512) void k_loss(const float* __restrict__ bufB,
                                              const float* __restrict__ minmax,
                                              float* __restrict__ acc,
                                              unsigned* __restrict__ count,
                                              float* __restrict__ out)
{
    __shared__ float sp[4096];
    __shared__ float st[4096];
    __shared__ float rs[8];

    int t = threadIdx.x;
    int r = blockIdx.x & 7;
    int k = blockIdx.x >> 3;
    int b = r + 8 * (k >> 6);
    int w = k & 63;
    int wi = w >> 3, wj = w & 7;

    int i0 = t << 3;
    int y = wi * 64 + (i0 >> 6);
    int x = wj * 64 + (i0 & 63);

    float mnP = minmax[2 * b],        mxP = minmax[2 * b + 1];
    float mnT = minmax[2 * (16 + b)], mxT = minmax[2 * (16 + b) + 1];
    float sclP = 1.0f / (mxP - mnP + 1e-6f);
    float sclT = 1.0f / (mxT - mnT + 1e-6f);

    float p[8], q[8];
    {
        const float4* P4 = (const float4*)(bufB + (long)b * 262144 + y * 512 + x);
        const float4* T4 = (const float4*)(bufB + (long)(16 + b) * 262144 + y * 512 + x);
        float4 a = P4[0], bb = P4[1], c = T4[0], d = T4[1];
        p[0]=a.x; p[1]=a.y; p[2]=a.z; p[3]=a.w; p[4]=bb.x; p[5]=bb.y; p[6]=bb.z; p[7]=bb.w;
        q[0]=c.x; q[1]=c.y; q[2]=c.z; q[3]=c.w; q[4]=d.x;  q[5]=d.y;  q[6]=d.z;  q[7]=d.w;
        #pragma unroll
        for (int e = 0; e < 8; ++e) {
            p[e] = (p[e] - mnP) * sclP;
            q[e] = (q[e] - mnT) * sclT;
        }
    }

    const float INFP = __builtin_inff();
    sort8asc(p); sort8asc(q);

    #pragma unroll 1
    for (int kk = 16; kk <= 4096; kk <<= 1) {
        int tmask = (kk - 1) >> 3;
        float sel = ((t & (kk >> 4)) == 0) ? -INFP : INFP;
        if (kk == 16)        { rdpp<0xB1>(p, sel); rdpp<0xB1>(q, sel); }
        else if (kk == 32)   { rdpp<0x1B>(p, sel); rdpp<0x1B>(q, sel); }
        else if (tmask < 64) { rshfl(p, tmask, sel); rshfl(q, tmask, sel); }
        else                 lstage(p, q, tmask, sel, true, sp, st, t);

        #pragma unroll 1
        for (int j = kk >> 2; j >= 8; j >>= 1) {
            int j8 = j >> 3;
            float s2 = ((t & j8) == 0) ? -INFP : INFP;
            if (j8 == 1)      { xdpp<0xB1>(p, s2); xdpp<0xB1>(q, s2); }
            else if (j8 == 2) { xdpp<0x4E>(p, s2); xdpp<0x4E>(q, s2); }
            else if (j8 < 64) { xshfl(p, j8, s2); xshfl(q, j8, s2); }
            else              lstage(p, q, j8, s2, false, sp, st, t);
        }
        merge8asc(p); merge8asc(q);
    }

    float s = 0.0f;
    #pragma unroll
    for (int e = 0; e < 8; ++e) { float d = p[e] - q[e]; s += d * d; }
    for (int o = 32; o > 0; o >>= 1) s += __shfl_down(s, o);
    if ((t & 63) == 0) rs[t >> 6] = s;
    __syncthreads();
    if (t == 0) {
        float tot = 0.0f;
        #pragma unroll
        for (int i = 0; i < 8; ++i) tot += rs[i];
        atomicAdd(acc, tot);
        __threadfence();
        unsigned done = atomicAdd(count, 1u);
        if (done == 1023u) {
            float total = atomicAdd(acc, 0.0f);
            float mean = total * (1.0f / 4194304.0f);
            out[0] = mean * 0.005f;
            out[1] = mean;
        }
    }
}

extern "C" void kernel_launch(void* const* d_in, const int* in_sizes, int n_in,
                              void* d_out, int out_size, void* d_ws, size_t ws_size,
                              hipStream_t stream)
{
    const float* pred = (const float*)d_in[0];
    const float* tgt  = (const float*)d_in[1];
    float* out = (float*)d_out;

    char* ws = (char*)d_ws;
    float* bufA     = (float*)ws;                       // 32 MB
    float* bufB     = (float*)(ws + (32ull << 20));     // 32 MB
    float* Cb       = (float*)(ws + (64ull << 20));     // 1 MB boundary rows (down)
    float* Db       = (float*)(ws + (65ull << 20));     // 1 MB boundary rows (up)
    float* minmax   = (float*)(ws + (66ull << 20));     // 64 floats
    float* acc      = minmax + 64;
    unsigned* count = (unsigned*)(acc + 1);

    k_init<<<16 * 1024, 256, 0, stream>>>(pred, tgt, bufA, acc, count, minmax);

    for (int s = 0; s < 4; ++s) {
        k_p1d  <<<512,   64, 0, stream>>>(bufA, Cb);
        k_comb <<< 32, 1024, 0, stream>>>(Cb, +1);
        k_p3d1u<<<512,   64, 0, stream>>>(bufA, bufB, Cb, Db);
        k_comb <<< 32, 1024, 0, stream>>>(Db, -1);
        k_p3u  <<<512,   64, 0, stream>>>(bufB, bufA, Db, minmax, s == 3 ? 1 : 0);
    }

    k_loss<<<1024, 512, 0, stream>>>(bufA, minmax, acc, count, out);
}